// Round 1
// baseline (391.926 us; speedup 1.0000x reference)
//
#include <hip/hip_runtime.h>
#include <hip/hip_bf16.h>

#define T_TOK 4096
#define DIM 1024
#define VOCAB 32000
#define BM 128
#define BN 128
#define BK 32
#define NVT (VOCAB / BN)   // 250 vocab tiles

typedef __attribute__((ext_vector_type(8))) short bf16x8;
typedef __attribute__((ext_vector_type(4))) float f32x4;

typedef __attribute__((address_space(1))) const unsigned int ga_u32;
typedef __attribute__((address_space(3))) unsigned int ls_u32;

__device__ __forceinline__ void gload16(const void* g, void* l) {
  __builtin_amdgcn_global_load_lds((ga_u32*)g, (ls_u32*)l, 16, 0, 0);
}

__device__ __forceinline__ float bf2f(short s) {
  unsigned u = ((unsigned)(unsigned short)s) << 16;
  return __uint_as_float(u);
}

// fp32 -> bf16 conversion, 4 elems/thread
__global__ void cvt_kernel(const float* __restrict__ in, __hip_bfloat16* __restrict__ out,
                           long long n) {
  long long i = ((long long)blockIdx.x * blockDim.x + threadIdx.x) * 4;
  if (i + 3 < n) {
    float4 v = *(const float4*)(in + i);
    union { ushort4 u; __hip_bfloat16 h[4]; } p;
    p.h[0] = __float2bfloat16(v.x);
    p.h[1] = __float2bfloat16(v.y);
    p.h[2] = __float2bfloat16(v.z);
    p.h[3] = __float2bfloat16(v.w);
    *(ushort4*)(out + i) = p.u;
  }
}

// 128x128 tile GEMM (A[T][D] x W[V][D]^T) + fused exp-row-sum epilogue.
// partial[vtile][token] = sum over this tile's 128 vocab cols of exp(logit+bias)
__global__ __launch_bounds__(256, 2) void gemm_ce_kernel(
    const __hip_bfloat16* __restrict__ A, const __hip_bfloat16* __restrict__ W,
    const float* __restrict__ bias, float* __restrict__ partial) {
  __shared__ __hip_bfloat16 Als[BM * BK];
  __shared__ __hip_bfloat16 Bls[BN * BK];
  __shared__ float red[BM][2];

  const int t = threadIdx.x;
  const int lane = t & 63;
  const int wid = t >> 6;
  const int wm = wid >> 1, wn = wid & 1;
  const int lr = lane & 15, lh = lane >> 4;
  const int m0 = blockIdx.y * BM;
  const int n0 = blockIdx.x * BN;

  const size_t arow = (size_t)(m0 + (t >> 2)) * DIM + (size_t)(t & 3) * 8;
  const size_t brow = (size_t)(n0 + (t >> 2)) * DIM + (size_t)(t & 3) * 8;

  f32x4 acc[4][4];
#pragma unroll
  for (int i = 0; i < 4; ++i)
#pragma unroll
    for (int j = 0; j < 4; ++j)
      acc[i][j] = (f32x4){0.f, 0.f, 0.f, 0.f};

  for (int k0 = 0; k0 < DIM; k0 += BK) {
    gload16(A + arow + k0, Als + t * 8);
    gload16(A + arow + (size_t)64 * DIM + k0, Als + 2048 + t * 8);
    gload16(W + brow + k0, Bls + t * 8);
    gload16(W + brow + (size_t)64 * DIM + k0, Bls + 2048 + t * 8);
    __syncthreads();
    bf16x8 a[4], b[4];
#pragma unroll
    for (int mi = 0; mi < 4; ++mi)
      a[mi] = *(const bf16x8*)(Als + (wm * 64 + mi * 16 + lr) * BK + lh * 8);
#pragma unroll
    for (int ni = 0; ni < 4; ++ni)
      b[ni] = *(const bf16x8*)(Bls + (wn * 64 + ni * 16 + lr) * BK + lh * 8);
#pragma unroll
    for (int mi = 0; mi < 4; ++mi)
#pragma unroll
      for (int ni = 0; ni < 4; ++ni)
        acc[mi][ni] =
            __builtin_amdgcn_mfma_f32_16x16x32_bf16(a[mi], b[ni], acc[mi][ni], 0, 0, 0);
    __syncthreads();
  }

  // Epilogue: per-row sum of exp(logit + bias) over this tile's 128 columns.
  // C/D layout (m89/m91): col = lane&15, row = (lane>>4)*4 + reg
#pragma unroll
  for (int mi = 0; mi < 4; ++mi) {
    float s0 = 0.f, s1 = 0.f, s2 = 0.f, s3 = 0.f;
#pragma unroll
    for (int ni = 0; ni < 4; ++ni) {
      float bcol = bias[n0 + wn * 64 + ni * 16 + lr];
      s0 += __expf(acc[mi][ni][0] + bcol);
      s1 += __expf(acc[mi][ni][1] + bcol);
      s2 += __expf(acc[mi][ni][2] + bcol);
      s3 += __expf(acc[mi][ni][3] + bcol);
    }
#pragma unroll
    for (int off = 1; off < 16; off <<= 1) {
      s0 += __shfl_xor(s0, off);
      s1 += __shfl_xor(s1, off);
      s2 += __shfl_xor(s2, off);
      s3 += __shfl_xor(s3, off);
    }
    if (lr == 0) {
      int rbase = wm * 64 + mi * 16 + lh * 4;
      red[rbase + 0][wn] = s0;
      red[rbase + 1][wn] = s1;
      red[rbase + 2][wn] = s2;
      red[rbase + 3][wn] = s3;
    }
  }
  __syncthreads();
  if (t < BM) {
    partial[(size_t)blockIdx.x * T_TOK + m0 + t] = red[t][0] + red[t][1];
  }
}

// tgt[t] = dot(Hb[t], Wb[labels[t]]) + bias[labels[t]]  (one wave per token)
__global__ void tgt_kernel(const __hip_bfloat16* __restrict__ H,
                           const __hip_bfloat16* __restrict__ W,
                           const float* __restrict__ bias, const int* __restrict__ labels,
                           float* __restrict__ tgt) {
  int tok = blockIdx.x * 4 + (threadIdx.x >> 6);
  int lane = threadIdx.x & 63;
  int lab = labels[tok];
  const __hip_bfloat16* h = H + (size_t)tok * DIM + lane * 16;
  const __hip_bfloat16* w = W + (size_t)lab * DIM + lane * 16;
  bf16x8 h0 = *(const bf16x8*)(h);
  bf16x8 h1 = *(const bf16x8*)(h + 8);
  bf16x8 w0 = *(const bf16x8*)(w);
  bf16x8 w1 = *(const bf16x8*)(w + 8);
  float s = 0.f;
#pragma unroll
  for (int j = 0; j < 8; ++j) s += bf2f(h0[j]) * bf2f(w0[j]);
#pragma unroll
  for (int j = 0; j < 8; ++j) s += bf2f(h1[j]) * bf2f(w1[j]);
#pragma unroll
  for (int off = 32; off > 0; off >>= 1) s += __shfl_xor(s, off);
  if (lane == 0) tgt[tok] = s + bias[lab];
}

// per-token: logz - tgt, weighted; wave-reduce -> per-block partials (deterministic)
__global__ void loss_a_kernel(const float* __restrict__ partial, const float* __restrict__ tgt,
                              const float* __restrict__ lw, float* __restrict__ npart,
                              float* __restrict__ dpart) {
  int tok = blockIdx.x * 64 + threadIdx.x;
  float s = 0.f;
  for (int v = 0; v < NVT; ++v) s += partial[(size_t)v * T_TOK + tok];
  float w = lw[tok];
  float num = w * (logf(s) - tgt[tok]);
#pragma unroll
  for (int off = 32; off > 0; off >>= 1) {
    num += __shfl_xor(num, off);
    w += __shfl_xor(w, off);
  }
  if (threadIdx.x == 0) {
    npart[blockIdx.x] = num;
    dpart[blockIdx.x] = w;
  }
}

__global__ void loss_b_kernel(const float* __restrict__ npart, const float* __restrict__ dpart,
                              float* __restrict__ out) {
  float num = npart[threadIdx.x];
  float den = dpart[threadIdx.x];
#pragma unroll
  for (int off = 32; off > 0; off >>= 1) {
    num += __shfl_xor(num, off);
    den += __shfl_xor(den, off);
  }
  if (threadIdx.x == 0) out[0] = num / den;
}

extern "C" void kernel_launch(void* const* d_in, const int* in_sizes, int n_in,
                              void* d_out, int out_size, void* d_ws, size_t ws_size,
                              hipStream_t stream) {
  const float* H = (const float*)d_in[0];
  const float* Wt = (const float*)d_in[1];
  const float* bias = (const float*)d_in[2];
  const int* labels = (const int*)d_in[3];
  const float* lw = (const float*)d_in[4];
  float* out = (float*)d_out;

  // ws layout (bytes):
  //   Wb   bf16 [VOCAB][DIM]   = 65,536,000
  //   Hb   bf16 [T_TOK][DIM]   =  8,388,608
  //   partial f32 [NVT][T_TOK] =  4,096,000
  //   tgt  f32 [T_TOK]         =     16,384
  //   npart/dpart f32 [64]x2
  char* ws = (char*)d_ws;
  __hip_bfloat16* Wb = (__hip_bfloat16*)ws;
  __hip_bfloat16* Hb = (__hip_bfloat16*)(ws + 65536000);
  float* partial = (float*)(ws + 65536000 + 8388608);
  float* tgt = (float*)(ws + 65536000 + 8388608 + 4096000);
  float* npart = tgt + T_TOK;
  float* dpart = npart + 64;

  hipLaunchKernelGGL(cvt_kernel, dim3(((long long)VOCAB * DIM) / 1024), dim3(256), 0, stream,
                     Wt, Wb, (long long)VOCAB * DIM);
  hipLaunchKernelGGL(cvt_kernel, dim3(((long long)T_TOK * DIM) / 1024), dim3(256), 0, stream,
                     H, Hb, (long long)T_TOK * DIM);
  hipLaunchKernelGGL(gemm_ce_kernel, dim3(NVT, T_TOK / BM), dim3(256), 0, stream,
                     Hb, Wb, bias, partial);
  hipLaunchKernelGGL(tgt_kernel, dim3(T_TOK / 4), dim3(256), 0, stream,
                     Hb, Wb, bias, labels, tgt);
  hipLaunchKernelGGL(loss_a_kernel, dim3(T_TOK / 64), dim3(64), 0, stream,
                     partial, tgt, lw, npart, dpart);
  hipLaunchKernelGGL(loss_b_kernel, dim3(1), dim3(64), 0, stream,
                     npart, dpart, out);
}

// Round 2
// 358.147 us; speedup vs baseline: 1.0943x; 1.0943x over previous
//
#include <hip/hip_runtime.h>
#include <hip/hip_bf16.h>

#define T_TOK 4096
#define DIM 1024
#define VOCAB 32000
#define BM 256
#define BN 256
#define NVT (VOCAB / BN)   // 125 vocab tiles
#define NMT (T_TOK / BM)   // 16 token tiles
#define NSL (DIM / 32)     // 32 k-slices

typedef __attribute__((ext_vector_type(8))) short bf16x8;
typedef __attribute__((ext_vector_type(4))) float f32x4;

typedef __attribute__((address_space(1))) const unsigned int ga_u32;
typedef __attribute__((address_space(3))) unsigned int ls_u32;

__device__ __forceinline__ void gload16(const void* g, void* l) {
  __builtin_amdgcn_global_load_lds((ga_u32*)g, (ls_u32*)l, 16, 0, 0);
}

template<int N> __device__ __forceinline__ void vmwait() {
  if constexpr (N == 8) asm volatile("s_waitcnt vmcnt(8)" ::: "memory");
  else if constexpr (N == 4) asm volatile("s_waitcnt vmcnt(4)" ::: "memory");
  else asm volatile("s_waitcnt vmcnt(0)" ::: "memory");
}

__device__ __forceinline__ float bf2f(short s) {
  unsigned u = ((unsigned)(unsigned short)s) << 16;
  return __uint_as_float(u);
}

// fp32 -> bf16 conversion, 4 elems/thread
__global__ void cvt_kernel(const float* __restrict__ in, __hip_bfloat16* __restrict__ out,
                           long long n) {
  long long i = ((long long)blockIdx.x * blockDim.x + threadIdx.x) * 4;
  if (i + 3 < n) {
    float4 v = *(const float4*)(in + i);
    union { ushort4 u; __hip_bfloat16 h[4]; } p;
    p.h[0] = __float2bfloat16(v.x);
    p.h[1] = __float2bfloat16(v.y);
    p.h[2] = __float2bfloat16(v.z);
    p.h[3] = __float2bfloat16(v.w);
    *(ushort4*)(out + i) = p.u;
  }
}

// 256x256-tile 8-wave GEMM, 4-deep k-slice LDS ring, counted vmcnt, LDS XOR-swizzle.
// partial[vtile][token] = sum over tile's 256 vocab cols of exp(logit + bias)
__global__ __launch_bounds__(512, 2) void gemm_ce_kernel(
    const __hip_bfloat16* __restrict__ A, const __hip_bfloat16* __restrict__ W,
    const float* __restrict__ bias, float* __restrict__ partial) {
  // ring of 4 k-slice chunks: A-slice [256][32], B-slice [256][32] bf16 each
  __shared__ __hip_bfloat16 Asl[4 * 8192];
  __shared__ __hip_bfloat16 Bsl[4 * 8192];
  __shared__ float red[BM][4];

  const int t = threadIdx.x;
  const int lane = t & 63;
  const int wid = t >> 6;        // 0..7
  const int wm = wid >> 2;       // 0..1  (M half)
  const int wn = wid & 3;        // 0..3  (N quarter)
  const int lr = lane & 15;
  const int lh = lane >> 4;      // 0..3 (k-quarter of 32-slice)
  // swizzled 16B-slot offset within a 64B row: slot' = lh ^ ((row>>1)&3); row%16==lr
  const int kq = ((lh ^ ((lr >> 1) & 3)) << 3);

  const int b = blockIdx.x;
  const int w = (b & 7) * 250 + (b >> 3);   // bijective XCD swizzle (2000 % 8 == 0)
  const int vt = w >> 4;                    // vt-major within XCD -> B-panel reuse
  const int mt = w & 15;
  const int m0 = mt * BM;
  const int n0 = vt * BN;

  // staging: thread t covers LDS bytes t*16 of each 8KB round; row=t>>2, 16B-slot=t&3
  const int srow = t >> 2;                  // 0..127
  const int sc16 = (t & 3) ^ ((srow >> 1) & 3);  // pre-swizzled global 16B-slot
  const __hip_bfloat16* agp = A + (size_t)(m0 + srow) * DIM + sc16 * 8;
  const __hip_bfloat16* bgp = W + (size_t)(n0 + srow) * DIM + sc16 * 8;

  int aoff[8], boff[4];
#pragma unroll
  for (int mi = 0; mi < 8; ++mi) aoff[mi] = (wm * 128 + mi * 16 + lr) * 32 + kq;
#pragma unroll
  for (int ni = 0; ni < 4; ++ni) boff[ni] = (wn * 64 + ni * 16 + lr) * 32 + kq;

  f32x4 acc[8][4];
#pragma unroll
  for (int i = 0; i < 8; ++i)
#pragma unroll
    for (int j = 0; j < 4; ++j) acc[i][j] = (f32x4){0.f, 0.f, 0.f, 0.f};

#define STAGE_A(JJ, R) \
  gload16(agp + (size_t)(R) * (128 * DIM) + (JJ) * 32, \
          Asl + ((JJ) & 3) * 8192 + (R) * 4096 + t * 8)
#define STAGE_B(JJ, R) \
  gload16(bgp + (size_t)(R) * (128 * DIM) + (JJ) * 32, \
          Bsl + ((JJ) & 3) * 8192 + (R) * 4096 + t * 8)

#define MM(mi, ni, av, bv) \
  acc[mi][ni] = __builtin_amdgcn_mfma_f32_16x16x32_bf16(av, bv, acc[mi][ni], 0, 0, 0);

  // body for one 32-wide k-slice: phase A (mi 0-3) + phase B (mi 4-7)
#define SLICE(J, VMN, DOSTAGE, DOTAIL) { \
    const __hip_bfloat16* As_ = Asl + ((J) & 3) * 8192; \
    const __hip_bfloat16* Bs_ = Bsl + ((J) & 3) * 8192; \
    bf16x8 a0_ = *(const bf16x8*)(As_ + aoff[0]); \
    bf16x8 a1_ = *(const bf16x8*)(As_ + aoff[1]); \
    bf16x8 a2_ = *(const bf16x8*)(As_ + aoff[2]); \
    bf16x8 a3_ = *(const bf16x8*)(As_ + aoff[3]); \
    bf16x8 b0_ = *(const bf16x8*)(Bs_ + boff[0]); \
    bf16x8 b1_ = *(const bf16x8*)(Bs_ + boff[1]); \
    bf16x8 b2_ = *(const bf16x8*)(Bs_ + boff[2]); \
    bf16x8 b3_ = *(const bf16x8*)(Bs_ + boff[3]); \
    if (DOSTAGE) { STAGE_A((J) + 3, 0); STAGE_A((J) + 3, 1); } \
    __builtin_amdgcn_s_setprio(1); \
    MM(0,0,a0_,b0_) MM(0,1,a0_,b1_) MM(0,2,a0_,b2_) MM(0,3,a0_,b3_) \
    MM(1,0,a1_,b0_) MM(1,1,a1_,b1_) MM(1,2,a1_,b2_) MM(1,3,a1_,b3_) \
    MM(2,0,a2_,b0_) MM(2,1,a2_,b1_) MM(2,2,a2_,b2_) MM(2,3,a2_,b3_) \
    MM(3,0,a3_,b0_) MM(3,1,a3_,b1_) MM(3,2,a3_,b2_) MM(3,3,a3_,b3_) \
    __builtin_amdgcn_s_setprio(0); \
    __builtin_amdgcn_s_barrier(); \
    bf16x8 a4_ = *(const bf16x8*)(As_ + aoff[4]); \
    bf16x8 a5_ = *(const bf16x8*)(As_ + aoff[5]); \
    bf16x8 a6_ = *(const bf16x8*)(As_ + aoff[6]); \
    bf16x8 a7_ = *(const bf16x8*)(As_ + aoff[7]); \
    if (DOSTAGE) { STAGE_B((J) + 3, 0); STAGE_B((J) + 3, 1); } \
    __builtin_amdgcn_s_setprio(1); \
    MM(4,0,a4_,b0_) MM(4,1,a4_,b1_) MM(4,2,a4_,b2_) MM(4,3,a4_,b3_) \
    MM(5,0,a5_,b0_) MM(5,1,a5_,b1_) MM(5,2,a5_,b2_) MM(5,3,a5_,b3_) \
    MM(6,0,a6_,b0_) MM(6,1,a6_,b1_) MM(6,2,a6_,b2_) MM(6,3,a6_,b3_) \
    MM(7,0,a7_,b0_) MM(7,1,a7_,b1_) MM(7,2,a7_,b2_) MM(7,3,a7_,b3_) \
    __builtin_amdgcn_s_setprio(0); \
    if (DOTAIL) { \
      vmwait<VMN>(); \
      __builtin_amdgcn_s_barrier(); \
      __builtin_amdgcn_sched_barrier(0); \
    } \
  }

  // prologue: stage slices 0,1,2 (12 gloads in flight), wait slice 0 (8 newer allowed)
#pragma unroll
  for (int s = 0; s < 3; ++s) {
    STAGE_A(s, 0); STAGE_A(s, 1); STAGE_B(s, 0); STAGE_B(s, 1);
  }
  vmwait<8>();
  __builtin_amdgcn_s_barrier();
  __builtin_amdgcn_sched_barrier(0);

  for (int j = 0; j < 29; ++j) {
    SLICE(j, 8, 1, 1);   // steady state: stage j+3, wait vmcnt(8) -> slice j+1 ready
  }
  SLICE(29, 4, 0, 1);    // no more stages: 8 outstanding, need slice 30 -> vmcnt(4)
  SLICE(30, 0, 0, 1);    // 4 outstanding, need slice 31 -> vmcnt(0)
  SLICE(31, 0, 0, 0);    // last slice, no tail

  // Epilogue: per token row, sum exp(logit+bias) over this tile's 256 vocab cols.
  // C/D layout: vocab col = lane&15 (+ni*16+wn*64), token row = (lane>>4)*4+reg (+mi*16+wm*128)
  __syncthreads();
  float bc[4];
#pragma unroll
  for (int ni = 0; ni < 4; ++ni) bc[ni] = bias[n0 + wn * 64 + ni * 16 + lr];
#pragma unroll
  for (int mi = 0; mi < 8; ++mi) {
    float s0 = 0.f, s1 = 0.f, s2 = 0.f, s3 = 0.f;
#pragma unroll
    for (int ni = 0; ni < 4; ++ni) {
      s0 += __expf(acc[mi][ni][0] + bc[ni]);
      s1 += __expf(acc[mi][ni][1] + bc[ni]);
      s2 += __expf(acc[mi][ni][2] + bc[ni]);
      s3 += __expf(acc[mi][ni][3] + bc[ni]);
    }
#pragma unroll
    for (int off = 1; off < 16; off <<= 1) {
      s0 += __shfl_xor(s0, off);
      s1 += __shfl_xor(s1, off);
      s2 += __shfl_xor(s2, off);
      s3 += __shfl_xor(s3, off);
    }
    if (lr == 0) {
      int rbase = wm * 128 + mi * 16 + lh * 4;
      red[rbase + 0][wn] = s0;
      red[rbase + 1][wn] = s1;
      red[rbase + 2][wn] = s2;
      red[rbase + 3][wn] = s3;
    }
  }
  __syncthreads();
  if (t < BM) {
    partial[(size_t)vt * T_TOK + m0 + t] = red[t][0] + red[t][1] + red[t][2] + red[t][3];
  }
}

// tgt[t] = dot(Hb[t], Wb[labels[t]]) + bias[labels[t]]  (one wave per token)
__global__ void tgt_kernel(const __hip_bfloat16* __restrict__ H,
                           const __hip_bfloat16* __restrict__ W,
                           const float* __restrict__ bias, const int* __restrict__ labels,
                           float* __restrict__ tgt) {
  int tok = blockIdx.x * 4 + (threadIdx.x >> 6);
  int lane = threadIdx.x & 63;
  int lab = labels[tok];
  const __hip_bfloat16* h = H + (size_t)tok * DIM + lane * 16;
  const __hip_bfloat16* w = W + (size_t)lab * DIM + lane * 16;
  bf16x8 h0 = *(const bf16x8*)(h);
  bf16x8 h1 = *(const bf16x8*)(h + 8);
  bf16x8 w0 = *(const bf16x8*)(w);
  bf16x8 w1 = *(const bf16x8*)(w + 8);
  float s = 0.f;
#pragma unroll
  for (int j = 0; j < 8; ++j) s += bf2f(h0[j]) * bf2f(w0[j]);
#pragma unroll
  for (int j = 0; j < 8; ++j) s += bf2f(h1[j]) * bf2f(w1[j]);
#pragma unroll
  for (int off = 32; off > 0; off >>= 1) s += __shfl_xor(s, off);
  if (lane == 0) tgt[tok] = s + bias[lab];
}

// per-token: logz - tgt, weighted; wave-reduce -> per-block partials (deterministic)
__global__ void loss_a_kernel(const float* __restrict__ partial, const float* __restrict__ tgt,
                              const float* __restrict__ lw, float* __restrict__ npart,
                              float* __restrict__ dpart) {
  int tok = blockIdx.x * 64 + threadIdx.x;
  float s = 0.f;
  for (int v = 0; v < NVT; ++v) s += partial[(size_t)v * T_TOK + tok];
  float w = lw[tok];
  float num = w * (logf(s) - tgt[tok]);
#pragma unroll
  for (int off = 32; off > 0; off >>= 1) {
    num += __shfl_xor(num, off);
    w += __shfl_xor(w, off);
  }
  if (threadIdx.x == 0) {
    npart[blockIdx.x] = num;
    dpart[blockIdx.x] = w;
  }
}

__global__ void loss_b_kernel(const float* __restrict__ npart, const float* __restrict__ dpart,
                              float* __restrict__ out) {
  float num = npart[threadIdx.x];
  float den = dpart[threadIdx.x];
#pragma unroll
  for (int off = 32; off > 0; off >>= 1) {
    num += __shfl_xor(num, off);
    den += __shfl_xor(den, off);
  }
  if (threadIdx.x == 0) out[0] = num / den;
}

extern "C" void kernel_launch(void* const* d_in, const int* in_sizes, int n_in,
                              void* d_out, int out_size, void* d_ws, size_t ws_size,
                              hipStream_t stream) {
  const float* H = (const float*)d_in[0];
  const float* Wt = (const float*)d_in[1];
  const float* bias = (const float*)d_in[2];
  const int* labels = (const int*)d_in[3];
  const float* lw = (const float*)d_in[4];
  float* out = (float*)d_out;

  char* ws = (char*)d_ws;
  __hip_bfloat16* Wb = (__hip_bfloat16*)ws;                       // 65,536,000 B
  __hip_bfloat16* Hb = (__hip_bfloat16*)(ws + 65536000);          //  8,388,608 B
  float* partial = (float*)(ws + 65536000 + 8388608);             //  2,048,000 B (125x4096)
  float* tgt = (float*)(ws + 65536000 + 8388608 + 4096000);
  float* npart = tgt + T_TOK;
  float* dpart = npart + 64;

  hipLaunchKernelGGL(cvt_kernel, dim3(((long long)VOCAB * DIM) / 1024), dim3(256), 0, stream,
                     Wt, Wb, (long long)VOCAB * DIM);
  hipLaunchKernelGGL(cvt_kernel, dim3(((long long)T_TOK * DIM) / 1024), dim3(256), 0, stream,
                     H, Hb, (long long)T_TOK * DIM);
  hipLaunchKernelGGL(gemm_ce_kernel, dim3(NVT * NMT), dim3(512), 0, stream,
                     Hb, Wb, bias, partial);
  hipLaunchKernelGGL(tgt_kernel, dim3(T_TOK / 4), dim3(256), 0, stream,
                     Hb, Wb, bias, labels, tgt);
  hipLaunchKernelGGL(loss_a_kernel, dim3(T_TOK / 64), dim3(64), 0, stream,
                     partial, tgt, lw, npart, dpart);
  hipLaunchKernelGGL(loss_b_kernel, dim3(1), dim3(64), 0, stream,
                     npart, dpart, out);
}